// Round 1
// 231.120 us; speedup vs baseline: 1.0005x; 1.0005x over previous
//
#include <hip/hip_runtime.h>

// ShortConvolution: depthwise causal conv1d (K=4) + SiLU
// x: (B=4, T=4096, D=2048) fp32, weight: (D, K) fp32, out: (B, T, D) fp32
// y[b,t,d] = silu( sum_k w[d,k] * x[b, t-3+k, d] )   (x[t<0] = 0)
//
// R3: R2's sched_barrier did NOT batch the loads (VGPR_Count=36 < 44 needed
// for 11 live f4 dests -> compiler serialized loads -> latency-bound 2.8 TB/s).
// Fix: issue all 15 loads as inline-asm global_load_dwordx4 (opaque to the
// compiler's s_waitcnt insertion, distinct "=&v" dests force them all in
// flight), then hand-placed FIFO waits.
//
// vmcnt bookkeeping (FIFO retire, m135): before iter i, ops issued =
// 4 q-loads + 11 r-loads + i stores = 15+i; must-complete = 4 q + r[0..i+3]
// = 8+i  =>  allowed outstanding = 7, CONSTANT for every iteration.
// (c==0 path: 12+i issued, 5+i needed -> also 7.)  The one-store-per-iter
// invariant is held by the "memory" clobber on the wait asm (stores cannot
// cross it); FMAs cannot hoist above the wait because sched_barrier(0)
// immediately follows it (rule #18).

#define B_DIM 4
#define T_DIM 4096
#define D_DIM 2048
#define K_DIM 4
#define TC    8                // timesteps per block

typedef float f4_t __attribute__((ext_vector_type(4)));

#define GLOAD(dst, voff, sbase) \
    asm volatile("global_load_dwordx4 %0, %1, %2" : "=&v"(dst) : "v"(voff), "s"(sbase))
#define GLOADO(dst, voff, sbase, o) \
    asm volatile("global_load_dwordx4 %0, %1, %2 offset:" #o : "=&v"(dst) : "v"(voff), "s"(sbase))

__global__ __launch_bounds__(512) void shortconv_silu_kernel(
    const float* __restrict__ x,
    const float* __restrict__ w,
    float* __restrict__ out)
{
    const int n_chunks = T_DIM / TC;          // 512
    const int b  = blockIdx.x / n_chunks;
    const int c  = blockIdx.x % n_chunks;
    const int t0 = c * TC;
    const int d4 = threadIdx.x;               // float4 index over D
    const int d0 = d4 * 4;

    const float* xb = x   + (size_t)b * T_DIM * D_DIM;
    float*       ob = out + (size_t)b * T_DIM * D_DIM;
    const int rowstride = D_DIM / 4;          // float4 elements per time row
    f4_t* ov = (f4_t*)ob + d4;

    // Per-lane byte offsets (row base goes in SGPRs: block-uniform).
    const unsigned lane_off = (unsigned)d0 * 4u;            // within a time row
    const unsigned w_off    = (unsigned)d0 * (K_DIM * 4u);  // into weight table

    f4_t q0, q1, q2, q3;
    f4_t r0, r1, r2, r3, r4, r5, r6, r7, r8, r9, r10;

    // ---- Issue ALL loads back-to-back. Weights first (needed first, L2-hot). ----
    GLOAD (q0, w_off, w);
    GLOADO(q1, w_off, w, 16);
    GLOADO(q2, w_off, w, 32);
    GLOADO(q3, w_off, w, 48);

    if (c == 0) {
        r0 = (f4_t)0.f; r1 = (f4_t)0.f; r2 = (f4_t)0.f;
        GLOAD(r3,  lane_off, xb + (size_t)(t0 + 0) * D_DIM);
        GLOAD(r4,  lane_off, xb + (size_t)(t0 + 1) * D_DIM);
        GLOAD(r5,  lane_off, xb + (size_t)(t0 + 2) * D_DIM);
        GLOAD(r6,  lane_off, xb + (size_t)(t0 + 3) * D_DIM);
        GLOAD(r7,  lane_off, xb + (size_t)(t0 + 4) * D_DIM);
        GLOAD(r8,  lane_off, xb + (size_t)(t0 + 5) * D_DIM);
        GLOAD(r9,  lane_off, xb + (size_t)(t0 + 6) * D_DIM);
        GLOAD(r10, lane_off, xb + (size_t)(t0 + 7) * D_DIM);
    } else {
        GLOAD(r0,  lane_off, xb + (size_t)(t0 - 3) * D_DIM);
        GLOAD(r1,  lane_off, xb + (size_t)(t0 - 2) * D_DIM);
        GLOAD(r2,  lane_off, xb + (size_t)(t0 - 1) * D_DIM);
        GLOAD(r3,  lane_off, xb + (size_t)(t0 + 0) * D_DIM);
        GLOAD(r4,  lane_off, xb + (size_t)(t0 + 1) * D_DIM);
        GLOAD(r5,  lane_off, xb + (size_t)(t0 + 2) * D_DIM);
        GLOAD(r6,  lane_off, xb + (size_t)(t0 + 3) * D_DIM);
        GLOAD(r7,  lane_off, xb + (size_t)(t0 + 4) * D_DIM);
        GLOAD(r8,  lane_off, xb + (size_t)(t0 + 5) * D_DIM);
        GLOAD(r9,  lane_off, xb + (size_t)(t0 + 6) * D_DIM);
        GLOAD(r10, lane_off, xb + (size_t)(t0 + 7) * D_DIM);
    }

    // ---- Compute + store, one row per iteration, progressive FIFO waits. ----
#define ITER(i, A, Bv, Cv, Dv)                                            \
    do {                                                                  \
        asm volatile("s_waitcnt vmcnt(7)" ::: "memory");                  \
        __builtin_amdgcn_sched_barrier(0);                                \
        f4_t y;                                                           \
        y.x = q0.x*(A).x + q0.y*(Bv).x + q0.z*(Cv).x + q0.w*(Dv).x;       \
        y.y = q1.x*(A).y + q1.y*(Bv).y + q1.z*(Cv).y + q1.w*(Dv).y;       \
        y.z = q2.x*(A).z + q2.y*(Bv).z + q2.z*(Cv).z + q2.w*(Dv).z;       \
        y.w = q3.x*(A).w + q3.y*(Bv).w + q3.z*(Cv).w + q3.w*(Dv).w;       \
        y.x = y.x / (1.f + __expf(-y.x));                                 \
        y.y = y.y / (1.f + __expf(-y.y));                                 \
        y.z = y.z / (1.f + __expf(-y.z));                                 \
        y.w = y.w / (1.f + __expf(-y.w));                                 \
        __builtin_nontemporal_store(y, &ov[(size_t)(t0 + (i)) * rowstride]); \
    } while (0)

    ITER(0, r0, r1, r2, r3);
    ITER(1, r1, r2, r3, r4);
    ITER(2, r2, r3, r4, r5);
    ITER(3, r3, r4, r5, r6);
    ITER(4, r4, r5, r6, r7);
    ITER(5, r5, r6, r7, r8);
    ITER(6, r6, r7, r8, r9);
    ITER(7, r7, r8, r9, r10);
#undef ITER
}

extern "C" void kernel_launch(void* const* d_in, const int* in_sizes, int n_in,
                              void* d_out, int out_size, void* d_ws, size_t ws_size,
                              hipStream_t stream) {
    const float* x = (const float*)d_in[0];
    const float* w = (const float*)d_in[1];
    float* out = (float*)d_out;

    const int n_chunks = T_DIM / TC;            // 512
    dim3 grid(B_DIM * n_chunks);                // 2048 blocks
    dim3 block(D_DIM / 4);                      // 512 threads
    shortconv_silu_kernel<<<grid, block, 0, stream>>>(x, w, out);
}

// Round 2
// 230.483 us; speedup vs baseline: 1.0033x; 1.0028x over previous
//
#include <hip/hip_runtime.h>

// ShortConvolution: depthwise causal conv1d (K=4) + SiLU
// x: (B=4, T=4096, D=2048) fp32, weight: (D, K) fp32, out: (B, T, D) fp32
// y[b,t,d] = silu( sum_k w[d,k] * x[b, t-3+k, d] )   (x[t<0] = 0)
//
// R4: R3 (11-deep forced load batch) was NEUTRAL -> concurrency was never
// the limiter. Little's law: resident waves generate ~10x the per-CU HBM
// share even latency-serialized; the service path itself is stuck at
// 2.8 TB/s. Prime suspect: __builtin_nontemporal_store bypasses L2, so
// 1 KiB NT writes from every wave interleave finely with read misses at
// the memory controller -> constant read/write bus turnaround -> ~2x DRAM
// efficiency loss. The 6.29 TB/s copy bench uses plain write-back stores
// (L2 batches evictions into long same-direction bursts); the 6.7 TB/s
// fill is pure-write. Single change vs R3: plain stores. vmcnt accounting
// unchanged (plain global_store also increments vmcnt; the "memory"
// clobber on each wait still pins one store per iteration).
//
// vmcnt bookkeeping (FIFO retire): before iter i, issued = 4 q + 11 r + i
// stores = 15+i; must-complete = 4 q + r[0..i+3] = 8+i => outstanding
// allowed = 7, constant. (c==0 path: 12+i issued, 5+i needed -> also 7.)

#define B_DIM 4
#define T_DIM 4096
#define D_DIM 2048
#define K_DIM 4
#define TC    8                // timesteps per block

typedef float f4_t __attribute__((ext_vector_type(4)));

#define GLOAD(dst, voff, sbase) \
    asm volatile("global_load_dwordx4 %0, %1, %2" : "=&v"(dst) : "v"(voff), "s"(sbase))
#define GLOADO(dst, voff, sbase, o) \
    asm volatile("global_load_dwordx4 %0, %1, %2 offset:" #o : "=&v"(dst) : "v"(voff), "s"(sbase))

__global__ __launch_bounds__(512) void shortconv_silu_kernel(
    const float* __restrict__ x,
    const float* __restrict__ w,
    float* __restrict__ out)
{
    const int n_chunks = T_DIM / TC;          // 512
    const int b  = blockIdx.x / n_chunks;
    const int c  = blockIdx.x % n_chunks;
    const int t0 = c * TC;
    const int d4 = threadIdx.x;               // float4 index over D
    const int d0 = d4 * 4;

    const float* xb = x   + (size_t)b * T_DIM * D_DIM;
    float*       ob = out + (size_t)b * T_DIM * D_DIM;
    const int rowstride = D_DIM / 4;          // float4 elements per time row
    f4_t* ov = (f4_t*)ob + d4;

    // Per-lane byte offsets (row base goes in SGPRs: block-uniform).
    const unsigned lane_off = (unsigned)d0 * 4u;            // within a time row
    const unsigned w_off    = (unsigned)d0 * (K_DIM * 4u);  // into weight table

    f4_t q0, q1, q2, q3;
    f4_t r0, r1, r2, r3, r4, r5, r6, r7, r8, r9, r10;

    // ---- Issue ALL loads back-to-back. Weights first (needed first, L2-hot). ----
    GLOAD (q0, w_off, w);
    GLOADO(q1, w_off, w, 16);
    GLOADO(q2, w_off, w, 32);
    GLOADO(q3, w_off, w, 48);

    if (c == 0) {
        r0 = (f4_t)0.f; r1 = (f4_t)0.f; r2 = (f4_t)0.f;
        GLOAD(r3,  lane_off, xb + (size_t)(t0 + 0) * D_DIM);
        GLOAD(r4,  lane_off, xb + (size_t)(t0 + 1) * D_DIM);
        GLOAD(r5,  lane_off, xb + (size_t)(t0 + 2) * D_DIM);
        GLOAD(r6,  lane_off, xb + (size_t)(t0 + 3) * D_DIM);
        GLOAD(r7,  lane_off, xb + (size_t)(t0 + 4) * D_DIM);
        GLOAD(r8,  lane_off, xb + (size_t)(t0 + 5) * D_DIM);
        GLOAD(r9,  lane_off, xb + (size_t)(t0 + 6) * D_DIM);
        GLOAD(r10, lane_off, xb + (size_t)(t0 + 7) * D_DIM);
    } else {
        GLOAD(r0,  lane_off, xb + (size_t)(t0 - 3) * D_DIM);
        GLOAD(r1,  lane_off, xb + (size_t)(t0 - 2) * D_DIM);
        GLOAD(r2,  lane_off, xb + (size_t)(t0 - 1) * D_DIM);
        GLOAD(r3,  lane_off, xb + (size_t)(t0 + 0) * D_DIM);
        GLOAD(r4,  lane_off, xb + (size_t)(t0 + 1) * D_DIM);
        GLOAD(r5,  lane_off, xb + (size_t)(t0 + 2) * D_DIM);
        GLOAD(r6,  lane_off, xb + (size_t)(t0 + 3) * D_DIM);
        GLOAD(r7,  lane_off, xb + (size_t)(t0 + 4) * D_DIM);
        GLOAD(r8,  lane_off, xb + (size_t)(t0 + 5) * D_DIM);
        GLOAD(r9,  lane_off, xb + (size_t)(t0 + 6) * D_DIM);
        GLOAD(r10, lane_off, xb + (size_t)(t0 + 7) * D_DIM);
    }

    // ---- Compute + store, one row per iteration, progressive FIFO waits. ----
#define ITER(i, A, Bv, Cv, Dv)                                            \
    do {                                                                  \
        asm volatile("s_waitcnt vmcnt(7)" ::: "memory");                  \
        __builtin_amdgcn_sched_barrier(0);                                \
        f4_t y;                                                           \
        y.x = q0.x*(A).x + q0.y*(Bv).x + q0.z*(Cv).x + q0.w*(Dv).x;       \
        y.y = q1.x*(A).y + q1.y*(Bv).y + q1.z*(Cv).y + q1.w*(Dv).y;       \
        y.z = q2.x*(A).z + q2.y*(Bv).z + q2.z*(Cv).z + q2.w*(Dv).z;       \
        y.w = q3.x*(A).w + q3.y*(Bv).w + q3.z*(Cv).w + q3.w*(Dv).w;       \
        y.x = y.x / (1.f + __expf(-y.x));                                 \
        y.y = y.y / (1.f + __expf(-y.y));                                 \
        y.z = y.z / (1.f + __expf(-y.z));                                 \
        y.w = y.w / (1.f + __expf(-y.w));                                 \
        ov[(size_t)(t0 + (i)) * rowstride] = y;  /* plain write-back store */ \
    } while (0)

    ITER(0, r0, r1, r2, r3);
    ITER(1, r1, r2, r3, r4);
    ITER(2, r2, r3, r4, r5);
    ITER(3, r3, r4, r5, r6);
    ITER(4, r4, r5, r6, r7);
    ITER(5, r5, r6, r7, r8);
    ITER(6, r6, r7, r8, r9);
    ITER(7, r7, r8, r9, r10);
#undef ITER
}

extern "C" void kernel_launch(void* const* d_in, const int* in_sizes, int n_in,
                              void* d_out, int out_size, void* d_ws, size_t ws_size,
                              hipStream_t stream) {
    const float* x = (const float*)d_in[0];
    const float* w = (const float*)d_in[1];
    float* out = (float*)d_out;

    const int n_chunks = T_DIM / TC;            // 512
    dim3 grid(B_DIM * n_chunks);                // 2048 blocks
    dim3 block(D_DIM / 4);                      // 512 threads
    shortconv_silu_kernel<<<grid, block, 0, stream>>>(x, w, out);
}